// Round 3
// baseline (292.027 us; speedup 1.0000x reference)
//
#include <hip/hip_runtime.h>
#include <stdint.h>
#include <stddef.h>

typedef _Float16 f16;
typedef _Float16 f16x2 __attribute__((ext_vector_type(2)));
typedef _Float16 f16x8 __attribute__((ext_vector_type(8)));
typedef float    f32x4 __attribute__((ext_vector_type(4)));

#define VOCAB 32000
#define EMBD  200
#define HID   128
#define NB    64
#define NT    64
#define G4    (4*HID)   // 512 gate width

__device__ __forceinline__ float sigf(float x) {
    return __builtin_amdgcn_rcpf(1.f + __expf(-x));
}
__device__ __forceinline__ float tanhf_(float x) {
    return 1.f - 2.f * __builtin_amdgcn_rcpf(1.f + __expf(2.f * x));
}

// pack recurrent weights into f16 pairs: wp[m][p][j] = (W[2p][j], W[2p+1][j])
__global__ __launch_bounds__(256) void prep_rec(
    const float* __restrict__ U0, const float* __restrict__ W1,
    const float* __restrict__ U1, uint32_t* __restrict__ wp) {
    int idx = blockIdx.x * 256 + threadIdx.x;
    if (idx >= 3 * 64 * G4) return;
    int m = idx >> 15;
    int rem = idx & 32767;
    int p = rem >> 9, j = rem & 511;
    const float* W = (m == 0) ? U0 : (m == 1) ? W1 : U1;
    f16x2 v;
    v[0] = (f16)W[(2 * p) * G4 + j];
    v[1] = (f16)W[(2 * p + 1) * G4 + j];
    ((f16x2*)wp)[idx] = v;
}

// transpose Wout f32 [128][32000] -> WoutT f16 [32000][128]
__global__ __launch_bounds__(256) void prep_woutT(
    const float* __restrict__ Wout, f16* __restrict__ WoutT) {
    __shared__ __align__(16) f16 tile[64 * 136];   // row stride 136 f16 = 272B
    const int n0 = blockIdx.x * 64;
    const int t = threadIdx.x;
    for (int i = t; i < 64 * 128; i += 256) {
        int k = i >> 6, n = i & 63;                 // consecutive t -> consecutive n (coalesced)
        tile[n * 136 + k] = (f16)Wout[(size_t)k * VOCAB + n0 + n];
    }
    __syncthreads();
    // 64 rows x 16 uint4-chunks (8 f16 each) = full 128-element rows
    for (int i = t; i < 1024; i += 256) {
        int n = i >> 4, u = i & 15;
        *(uint4*)(WoutT + (size_t)(n0 + n) * HID + u * 8) =
            *(const uint4*)&tile[n * 136 + u * 8];
    }
}

// phase 1: z0base = emb[tokens] @ W0 + b0  (fp32)
__global__ __launch_bounds__(256) void embed_w0(
    const int* __restrict__ tokens, const float* __restrict__ emb,
    const float* __restrict__ W0, const float* __restrict__ b0,
    float* __restrict__ z0) {
    __shared__ __align__(16) float xs[EMBD * 16];   // [k][r]
    __shared__ int tok[16];
    const int t = threadIdx.x, blk = blockIdx.x;
    if (t < 16) tok[t] = tokens[blk * 16 + t];
    __syncthreads();
    for (int i = t; i < EMBD * 16; i += 256) {
        int r = i / EMBD, k = i - r * EMBD;
        xs[k * 16 + r] = emb[(size_t)tok[r] * EMBD + k];
    }
    __syncthreads();
    const int j = t * 2;
    f32x4 accA[4], accB[4];
#pragma unroll
    for (int grp = 0; grp < 4; ++grp) {
        accA[grp] = f32x4{0.f, 0.f, 0.f, 0.f};
        accB[grp] = f32x4{0.f, 0.f, 0.f, 0.f};
    }
    for (int k = 0; k < EMBD; ++k) {
        float2 w = *(const float2*)(W0 + (size_t)k * G4 + j);
        const f32x4* xv = (const f32x4*)(xs + k * 16);
#pragma unroll
        for (int grp = 0; grp < 4; ++grp) {
            f32x4 x = xv[grp];
            accA[grp] += x * w.x;
            accB[grp] += x * w.y;
        }
    }
    float bx = b0[j], by = b0[j + 1];
#pragma unroll
    for (int grp = 0; grp < 4; ++grp)
#pragma unroll
        for (int r = 0; r < 4; ++r) {
            int row = blk * 16 + grp * 4 + r;
            float2 o; o.x = accA[grp][r] + bx; o.y = accB[grp][r] + by;
            *(float2*)(z0 + (size_t)row * G4 + j) = o;
        }
}

// phase 2: sequential LSTM scan, one block per batch element.
// Weights register-resident (192 f16x2/thread) -> needs VGPR cap 512: launch_bounds(512,1).
// 4 barriers per step; gate threads (t<128) read z0/b1 direct from global, partials from LDS.
__global__ __launch_bounds__(512, 1) void lstm_scan(
    const float* __restrict__ z0base, const uint32_t* __restrict__ wp,
    const float* __restrict__ b1, f16* __restrict__ H1) {
    const int b = blockIdx.x, t = threadIdx.x;
    const int g = t >> 7, q = t & 127, jb = q << 2;
    __shared__ __align__(16) float zpart[4][G4];    // 8 KB
    __shared__ __align__(16) f16 h0s[HID];
    __shared__ __align__(16) f16 h1s[HID];

    const f16x8* wp8 = (const f16x8*)wp;
    f16x2 wu0[64], ww1[64], wu1[64];                // 192 VGPRs of weights
    const int wbase = (g * 16) * 128 + q;
#pragma unroll
    for (int kk = 0; kk < 16; ++kk) {
        *(f16x8*)&wu0[kk * 4] = wp8[0 * 8192 + wbase + kk * 128];
        *(f16x8*)&ww1[kk * 4] = wp8[1 * 8192 + wbase + kk * 128];
        *(f16x8*)&wu1[kk * 4] = wp8[2 * 8192 + wbase + kk * 128];
    }
    float b1a = 0.f, b1b = 0.f, b1c = 0.f, b1d = 0.f;
    if (t < HID) {
        b1a = b1[t]; b1b = b1[t + 128]; b1c = b1[t + 256]; b1d = b1[t + 384];
        h0s[t] = (f16)0.f; h1s[t] = (f16)0.f;
    }
    float c0 = 0.f, c1 = 0.f;
    __syncthreads();

    const float* zb = z0base + (size_t)b * NT * G4;
    f16* hout = H1 + (size_t)b * NT * HID;

    for (int step = 0; step < NT; ++step) {
        // prefetch this step's z0 terms (used after phase A; latency hides under dots)
        float za = 0.f, zbv = 0.f, zc = 0.f, zd = 0.f;
        if (t < HID) {
            const float* zr = zb + (size_t)step * G4 + t;
            za = zr[0]; zbv = zr[128]; zc = zr[256]; zd = zr[384];
        }
        // ---- phase A: layer-0 partial dots h0_old . U0 ----
        float a0 = 0.f, a1 = 0.f, a2 = 0.f, a3 = 0.f;
        {
            f16x2 hh[16];
            const f16x8* hp = (const f16x8*)h0s + g * 4;
            *(f16x8*)&hh[0] = hp[0]; *(f16x8*)&hh[4] = hp[1];
            *(f16x8*)&hh[8] = hp[2]; *(f16x8*)&hh[12] = hp[3];
#pragma unroll
            for (int kk = 0; kk < 16; ++kk) {
                f16x2 h = hh[kk];
                a0 = __builtin_amdgcn_fdot2(wu0[kk * 4 + 0], h, a0, false);
                a1 = __builtin_amdgcn_fdot2(wu0[kk * 4 + 1], h, a1, false);
                a2 = __builtin_amdgcn_fdot2(wu0[kk * 4 + 2], h, a2, false);
                a3 = __builtin_amdgcn_fdot2(wu0[kk * 4 + 3], h, a3, false);
            }
        }
        *(f32x4*)&zpart[g][jb] = f32x4{a0, a1, a2, a3};
        __syncthreads();                                           // 1
        // ---- phase B: layer-0 gates (t<128) ----
        if (t < HID) {
            float zi = za  + zpart[0][t]       + zpart[1][t]       + zpart[2][t]       + zpart[3][t];
            float zf = zbv + zpart[0][t + 128] + zpart[1][t + 128] + zpart[2][t + 128] + zpart[3][t + 128];
            float zg = zc  + zpart[0][t + 256] + zpart[1][t + 256] + zpart[2][t + 256] + zpart[3][t + 256];
            float zo = zd  + zpart[0][t + 384] + zpart[1][t + 384] + zpart[2][t + 384] + zpart[3][t + 384];
            c0 = sigf(zf) * c0 + sigf(zi) * tanhf_(zg);
            h0s[t] = (f16)(sigf(zo) * tanhf_(c0));
        }
        __syncthreads();                                           // 2
        // ---- phase C: layer-1 partial dots h0_new.W1 + h1_old.U1 ----
        a0 = 0.f; a1 = 0.f; a2 = 0.f; a3 = 0.f;
        {
            f16x2 hh[16];
            const f16x8* hp0 = (const f16x8*)h0s + g * 4;
            *(f16x8*)&hh[0] = hp0[0]; *(f16x8*)&hh[4] = hp0[1];
            *(f16x8*)&hh[8] = hp0[2]; *(f16x8*)&hh[12] = hp0[3];
#pragma unroll
            for (int kk = 0; kk < 16; ++kk) {
                f16x2 h = hh[kk];
                a0 = __builtin_amdgcn_fdot2(ww1[kk * 4 + 0], h, a0, false);
                a1 = __builtin_amdgcn_fdot2(ww1[kk * 4 + 1], h, a1, false);
                a2 = __builtin_amdgcn_fdot2(ww1[kk * 4 + 2], h, a2, false);
                a3 = __builtin_amdgcn_fdot2(ww1[kk * 4 + 3], h, a3, false);
            }
            const f16x8* hp1 = (const f16x8*)h1s + g * 4;
            *(f16x8*)&hh[0] = hp1[0]; *(f16x8*)&hh[4] = hp1[1];
            *(f16x8*)&hh[8] = hp1[2]; *(f16x8*)&hh[12] = hp1[3];
#pragma unroll
            for (int kk = 0; kk < 16; ++kk) {
                f16x2 h = hh[kk];
                a0 = __builtin_amdgcn_fdot2(wu1[kk * 4 + 0], h, a0, false);
                a1 = __builtin_amdgcn_fdot2(wu1[kk * 4 + 1], h, a1, false);
                a2 = __builtin_amdgcn_fdot2(wu1[kk * 4 + 2], h, a2, false);
                a3 = __builtin_amdgcn_fdot2(wu1[kk * 4 + 3], h, a3, false);
            }
        }
        *(f32x4*)&zpart[g][jb] = f32x4{a0, a1, a2, a3};
        __syncthreads();                                           // 3
        // ---- phase D: layer-1 gates (t<128) ----
        if (t < HID) {
            float zi = b1a + zpart[0][t]       + zpart[1][t]       + zpart[2][t]       + zpart[3][t];
            float zf = b1b + zpart[0][t + 128] + zpart[1][t + 128] + zpart[2][t + 128] + zpart[3][t + 128];
            float zg = b1c + zpart[0][t + 256] + zpart[1][t + 256] + zpart[2][t + 256] + zpart[3][t + 256];
            float zo = b1d + zpart[0][t + 384] + zpart[1][t + 384] + zpart[2][t + 384] + zpart[3][t + 384];
            c1 = sigf(zf) * c1 + sigf(zi) * tanhf_(zg);
            float h1v = sigf(zo) * tanhf_(c1);
            h1s[t] = (f16)h1v;
            hout[step * HID + t] = (f16)h1v;
        }
        __syncthreads();                                           // 4
    }
}

// phase 3: out = relu(H1 @ Wout + bout) via f16 MFMA, tile 128x128, K=128 one-shot
__global__ __launch_bounds__(256) void out_gemm(
    const f16* __restrict__ H1, const f16* __restrict__ WT,
    const float* __restrict__ bout, float* __restrict__ out) {
    __shared__ __align__(16) f16 Asub[128 * 128];
    __shared__ __align__(16) f16 Bsub[128 * 128];
    const int n0 = blockIdx.x * 128;
    const int m0 = blockIdx.y * 128;
    const int t = threadIdx.x;

    const uint4* Ag = (const uint4*)(H1 + (size_t)m0 * HID);
    const uint4* Bg = (const uint4*)(WT + (size_t)n0 * HID);
#pragma unroll
    for (int i = 0; i < 8; ++i) {
        int Gr = i * 256 + t;
        int row = Gr >> 4, gg = Gr & 15;
        int d = (row << 4) | (gg ^ (row & 7));   // XOR granule swizzle (T2-style)
        ((uint4*)Asub)[d] = Ag[Gr];
        ((uint4*)Bsub)[d] = Bg[Gr];
    }
    __syncthreads();

    const int w = t >> 6, l = t & 63;
    const int wm = (w >> 1) * 64, wn = (w & 1) * 64;
    const int lr = l & 15, lk = l >> 4;
    f32x4 zero = {0.f, 0.f, 0.f, 0.f};
    f32x4 acc[4][4];
#pragma unroll
    for (int mi = 0; mi < 4; ++mi)
#pragma unroll
        for (int ni = 0; ni < 4; ++ni) acc[mi][ni] = zero;

#pragma unroll
    for (int kc = 0; kc < 4; ++kc) {
        f16x8 af[4], bf[4];
#pragma unroll
        for (int mi = 0; mi < 4; ++mi) {
            int row = wm + mi * 16 + lr;
            int gg = kc * 4 + lk;
            af[mi] = *(const f16x8*)&Asub[(row << 7) + ((gg ^ (row & 7)) << 3)];
        }
#pragma unroll
        for (int ni = 0; ni < 4; ++ni) {
            int row = wn + ni * 16 + lr;
            int gg = kc * 4 + lk;
            bf[ni] = *(const f16x8*)&Bsub[(row << 7) + ((gg ^ (row & 7)) << 3)];
        }
#pragma unroll
        for (int mi = 0; mi < 4; ++mi)
#pragma unroll
            for (int ni = 0; ni < 4; ++ni)
                acc[mi][ni] = __builtin_amdgcn_mfma_f32_16x16x32_f16(
                    af[mi], bf[ni], acc[mi][ni], 0, 0, 0);
    }

#pragma unroll
    for (int ni = 0; ni < 4; ++ni) {
        int n = n0 + wn + ni * 16 + lr;
        float bv = bout[n];
#pragma unroll
        for (int mi = 0; mi < 4; ++mi) {
            int mrow = m0 + wm + mi * 16 + lk * 4;
#pragma unroll
            for (int r = 0; r < 4; ++r) {
                float v = acc[mi][ni][r] + bv;
                __builtin_nontemporal_store(v > 0.f ? v : 0.f,
                                            &out[(size_t)(mrow + r) * VOCAB + n]);
            }
        }
    }
}

extern "C" void kernel_launch(void* const* d_in, const int* in_sizes, int n_in,
                              void* d_out, int out_size, void* d_ws, size_t ws_size,
                              hipStream_t stream) {
    const int*   tokens = (const int*)d_in[0];
    const float* emb  = (const float*)d_in[1];
    const float* W0   = (const float*)d_in[2];
    const float* U0   = (const float*)d_in[3];
    const float* b0   = (const float*)d_in[4];
    const float* W1   = (const float*)d_in[5];
    const float* U1   = (const float*)d_in[6];
    const float* b1   = (const float*)d_in[7];
    const float* Wout = (const float*)d_in[8];
    const float* bout = (const float*)d_in[9];
    float* out = (float*)d_out;

    // ws layout: [0, 8.39MB) = z0base f32 (phase1/2), reused as WoutT f16 (phase3)
    char* ws = (char*)d_ws;
    float*    z0base = (float*)ws;
    f16*      WoutT  = (f16*)ws;                   // aliases z0base (dead after scan)
    uint32_t* wp     = (uint32_t*)(ws + 8388608);
    f16*      H1     = (f16*)(ws + 8781824);       // total ws use ~9.4 MB

    embed_w0  <<<256, 256, 0, stream>>>(tokens, emb, W0, b0, z0base);
    prep_rec  <<<384, 256, 0, stream>>>(U0, W1, U1, wp);
    lstm_scan <<<64, 512, 0, stream>>>(z0base, wp, b1, H1);
    prep_woutT<<<500, 256, 0, stream>>>(Wout, WoutT);
    out_gemm  <<<dim3(250, 32), 256, 0, stream>>>(H1, WoutT, bout, out);
}

// Round 4
// 274.421 us; speedup vs baseline: 1.0642x; 1.0642x over previous
//
#include <hip/hip_runtime.h>
#include <stdint.h>
#include <stddef.h>

typedef _Float16 f16;
typedef _Float16 f16x2 __attribute__((ext_vector_type(2)));
typedef _Float16 f16x8 __attribute__((ext_vector_type(8)));
typedef float    f32x4 __attribute__((ext_vector_type(4)));

#define VOCAB 32000
#define EMBD  200
#define HID   128
#define NB    64
#define NT    64
#define G4    (4*HID)   // 512 gate width

__device__ __forceinline__ float sigf(float x) {
    return __builtin_amdgcn_rcpf(1.f + __expf(-x));
}
__device__ __forceinline__ float tanhf_(float x) {
    return 1.f - 2.f * __builtin_amdgcn_rcpf(1.f + __expf(2.f * x));
}

// fused prep: blocks [0,256) = embed_w0 (z0 = emb[tokens]@W0 + b0),
//             blocks [256,640) = prep_rec (pack U0,W1,U1 into f16 pairs)
__global__ __launch_bounds__(256) void fused_prep(
    const int* __restrict__ tokens, const float* __restrict__ emb,
    const float* __restrict__ W0, const float* __restrict__ b0,
    const float* __restrict__ U0, const float* __restrict__ W1,
    const float* __restrict__ U1,
    float* __restrict__ z0, uint32_t* __restrict__ wp) {
    const int t = threadIdx.x;
    if (blockIdx.x >= 256) {
        // ---- prep_rec ----
        int idx = (blockIdx.x - 256) * 256 + t;       // [0, 98304)
        int m = idx >> 15;
        int rem = idx & 32767;
        int p = rem >> 9, j = rem & 511;
        const float* W = (m == 0) ? U0 : (m == 1) ? W1 : U1;
        f16x2 v;
        v[0] = (f16)W[(2 * p) * G4 + j];
        v[1] = (f16)W[(2 * p + 1) * G4 + j];
        ((f16x2*)wp)[idx] = v;
        return;
    }
    // ---- embed_w0 ----
    __shared__ __align__(16) float xs[EMBD * 16];   // [k][r]
    __shared__ int tok[16];
    const int blk = blockIdx.x;
    if (t < 16) tok[t] = tokens[blk * 16 + t];
    __syncthreads();
    for (int i = t; i < EMBD * 16; i += 256) {
        int r = i / EMBD, k = i - r * EMBD;
        xs[k * 16 + r] = emb[(size_t)tok[r] * EMBD + k];
    }
    __syncthreads();
    const int j = t * 2;
    f32x4 accA[4], accB[4];
#pragma unroll
    for (int grp = 0; grp < 4; ++grp) {
        accA[grp] = f32x4{0.f, 0.f, 0.f, 0.f};
        accB[grp] = f32x4{0.f, 0.f, 0.f, 0.f};
    }
    for (int k = 0; k < EMBD; ++k) {
        float2 w = *(const float2*)(W0 + (size_t)k * G4 + j);
        const f32x4* xv = (const f32x4*)(xs + k * 16);
#pragma unroll
        for (int grp = 0; grp < 4; ++grp) {
            f32x4 x = xv[grp];
            accA[grp] += x * w.x;
            accB[grp] += x * w.y;
        }
    }
    float bx = b0[j], by = b0[j + 1];
#pragma unroll
    for (int grp = 0; grp < 4; ++grp)
#pragma unroll
        for (int r = 0; r < 4; ++r) {
            int row = blk * 16 + grp * 4 + r;
            float2 o; o.x = accA[grp][r] + bx; o.y = accB[grp][r] + by;
            *(float2*)(z0 + (size_t)row * G4 + j) = o;
        }
}

// scan (blocks 0..63, one per batch element) fused with Wout transpose
// (blocks 64..563, run on otherwise-idle CUs while the scan grinds).
__global__ __launch_bounds__(512, 1) void scan_fused(
    const float* __restrict__ z0base, const uint32_t* __restrict__ wp,
    const float* __restrict__ b1, f16* __restrict__ H1,
    const float* __restrict__ Wout, f16* __restrict__ WoutT, int do_wt) {
    const int t = threadIdx.x;
    if (blockIdx.x >= 64) {
        if (!do_wt) return;
        // ---- transpose Wout f32 [128][32000] -> WoutT f16 [32000][128] ----
        __shared__ __align__(16) f16 tile[64 * 136];
        const int n0 = (blockIdx.x - 64) * 64;
        for (int i = t; i < 64 * 128; i += 512) {
            int k = i >> 6, n = i & 63;
            tile[n * 136 + k] = (f16)Wout[(size_t)k * VOCAB + n0 + n];
        }
        __syncthreads();
        for (int i = t; i < 1024; i += 512) {
            int n = i >> 4, u = i & 15;
            *(uint4*)(WoutT + (size_t)(n0 + n) * HID + u * 8) =
                *(const uint4*)&tile[n * 136 + u * 8];
        }
        return;
    }
    // ---- LSTM scan ----
    const int b = blockIdx.x;
    const int g = t >> 7, q = t & 127, jb = q << 2;
    __shared__ __align__(16) float zpart[4][G4];    // 8 KB
    __shared__ __align__(16) f16 h0s[HID];
    __shared__ __align__(16) f16 h1s[HID];

    const f16x8* wp8 = (const f16x8*)wp;
    f16x2 wu0[64], ww1[64], wu1[64];                // 192 VGPRs of weights
    const int wbase = (g * 16) * 128 + q;
#pragma unroll
    for (int kk = 0; kk < 16; ++kk) {
        *(f16x8*)&wu0[kk * 4] = wp8[0 * 8192 + wbase + kk * 128];
        *(f16x8*)&ww1[kk * 4] = wp8[1 * 8192 + wbase + kk * 128];
        *(f16x8*)&wu1[kk * 4] = wp8[2 * 8192 + wbase + kk * 128];
    }
    float b1a = 0.f, b1b = 0.f, b1c = 0.f, b1d = 0.f;
    if (t < HID) {
        b1a = b1[t]; b1b = b1[t + 128]; b1c = b1[t + 256]; b1d = b1[t + 384];
        h0s[t] = (f16)0.f; h1s[t] = (f16)0.f;
    }
    float c0 = 0.f, c1 = 0.f;
    __syncthreads();

    const float* zb = z0base + (size_t)b * NT * G4;
    f16* hout = H1 + (size_t)b * NT * HID;

    for (int step = 0; step < NT; ++step) {
        float za = 0.f, zbv = 0.f, zc = 0.f, zd = 0.f;
        if (t < HID) {
            const float* zr = zb + (size_t)step * G4 + t;
            za = zr[0]; zbv = zr[128]; zc = zr[256]; zd = zr[384];
        }
        // phase A: layer-0 partial dots h0_old . U0
        float a0 = 0.f, a1 = 0.f, a2 = 0.f, a3 = 0.f;
        {
            f16x2 hh[16];
            const f16x8* hp = (const f16x8*)h0s + g * 4;
            *(f16x8*)&hh[0] = hp[0]; *(f16x8*)&hh[4] = hp[1];
            *(f16x8*)&hh[8] = hp[2]; *(f16x8*)&hh[12] = hp[3];
#pragma unroll
            for (int kk = 0; kk < 16; ++kk) {
                f16x2 h = hh[kk];
                a0 = __builtin_amdgcn_fdot2(wu0[kk * 4 + 0], h, a0, false);
                a1 = __builtin_amdgcn_fdot2(wu0[kk * 4 + 1], h, a1, false);
                a2 = __builtin_amdgcn_fdot2(wu0[kk * 4 + 2], h, a2, false);
                a3 = __builtin_amdgcn_fdot2(wu0[kk * 4 + 3], h, a3, false);
            }
        }
        *(f32x4*)&zpart[g][jb] = f32x4{a0, a1, a2, a3};
        __syncthreads();                                           // 1
        // phase B: layer-0 gates
        if (t < HID) {
            float zi = za  + zpart[0][t]       + zpart[1][t]       + zpart[2][t]       + zpart[3][t];
            float zf = zbv + zpart[0][t + 128] + zpart[1][t + 128] + zpart[2][t + 128] + zpart[3][t + 128];
            float zg = zc  + zpart[0][t + 256] + zpart[1][t + 256] + zpart[2][t + 256] + zpart[3][t + 256];
            float zo = zd  + zpart[0][t + 384] + zpart[1][t + 384] + zpart[2][t + 384] + zpart[3][t + 384];
            c0 = sigf(zf) * c0 + sigf(zi) * tanhf_(zg);
            h0s[t] = (f16)(sigf(zo) * tanhf_(c0));
        }
        __syncthreads();                                           // 2
        // phase C: layer-1 partial dots h0_new.W1 + h1_old.U1
        a0 = 0.f; a1 = 0.f; a2 = 0.f; a3 = 0.f;
        {
            f16x2 hh[16];
            const f16x8* hp0 = (const f16x8*)h0s + g * 4;
            *(f16x8*)&hh[0] = hp0[0]; *(f16x8*)&hh[4] = hp0[1];
            *(f16x8*)&hh[8] = hp0[2]; *(f16x8*)&hh[12] = hp0[3];
#pragma unroll
            for (int kk = 0; kk < 16; ++kk) {
                f16x2 h = hh[kk];
                a0 = __builtin_amdgcn_fdot2(ww1[kk * 4 + 0], h, a0, false);
                a1 = __builtin_amdgcn_fdot2(ww1[kk * 4 + 1], h, a1, false);
                a2 = __builtin_amdgcn_fdot2(ww1[kk * 4 + 2], h, a2, false);
                a3 = __builtin_amdgcn_fdot2(ww1[kk * 4 + 3], h, a3, false);
            }
            const f16x8* hp1 = (const f16x8*)h1s + g * 4;
            *(f16x8*)&hh[0] = hp1[0]; *(f16x8*)&hh[4] = hp1[1];
            *(f16x8*)&hh[8] = hp1[2]; *(f16x8*)&hh[12] = hp1[3];
#pragma unroll
            for (int kk = 0; kk < 16; ++kk) {
                f16x2 h = hh[kk];
                a0 = __builtin_amdgcn_fdot2(wu1[kk * 4 + 0], h, a0, false);
                a1 = __builtin_amdgcn_fdot2(wu1[kk * 4 + 1], h, a1, false);
                a2 = __builtin_amdgcn_fdot2(wu1[kk * 4 + 2], h, a2, false);
                a3 = __builtin_amdgcn_fdot2(wu1[kk * 4 + 3], h, a3, false);
            }
        }
        *(f32x4*)&zpart[g][jb] = f32x4{a0, a1, a2, a3};
        __syncthreads();                                           // 3
        // phase D: layer-1 gates + H1 store
        if (t < HID) {
            float zi = b1a + zpart[0][t]       + zpart[1][t]       + zpart[2][t]       + zpart[3][t];
            float zf = b1b + zpart[0][t + 128] + zpart[1][t + 128] + zpart[2][t + 128] + zpart[3][t + 128];
            float zg = b1c + zpart[0][t + 256] + zpart[1][t + 256] + zpart[2][t + 256] + zpart[3][t + 256];
            float zo = b1d + zpart[0][t + 384] + zpart[1][t + 384] + zpart[2][t + 384] + zpart[3][t + 384];
            c1 = sigf(zf) * c1 + sigf(zi) * tanhf_(zg);
            float h1v = sigf(zo) * tanhf_(c1);
            h1s[t] = (f16)h1v;
            hout[step * HID + t] = (f16)h1v;
        }
        __syncthreads();                                           // 4
    }
}

// fallback transpose kernel (used only if ws is too small to avoid aliasing)
__global__ __launch_bounds__(256) void prep_woutT(
    const float* __restrict__ Wout, f16* __restrict__ WoutT) {
    __shared__ __align__(16) f16 tile[64 * 136];
    const int n0 = blockIdx.x * 64;
    const int t = threadIdx.x;
    for (int i = t; i < 64 * 128; i += 256) {
        int k = i >> 6, n = i & 63;
        tile[n * 136 + k] = (f16)Wout[(size_t)k * VOCAB + n0 + n];
    }
    __syncthreads();
    for (int i = t; i < 1024; i += 256) {
        int n = i >> 4, u = i & 15;
        *(uint4*)(WoutT + (size_t)(n0 + n) * HID + u * 8) =
            *(const uint4*)&tile[n * 136 + u * 8];
    }
}

// out = relu(H1 @ Wout + bout) via f16 MFMA, tile 128x128, K=128 one-shot.
// Grid (32 m, 250 n): consecutive blocks share the B-tile (L2 reuse).
// Epilogue transposes acc through LDS so stores are contiguous 512B runs.
__global__ __launch_bounds__(256) void out_gemm(
    const f16* __restrict__ H1, const f16* __restrict__ WT,
    const float* __restrict__ bout, float* __restrict__ out) {
    __shared__ __align__(16) char lraw[128 * 132 * 4];   // 67.6 KB, reused
    f16* Asub = (f16*)lraw;
    f16* Bsub = (f16*)(lraw + 32768);
    const int m0 = blockIdx.x * 128;
    const int n0 = blockIdx.y * 128;
    const int t = threadIdx.x;

    const uint4* Ag = (const uint4*)(H1 + (size_t)m0 * HID);
    const uint4* Bg = (const uint4*)(WT + (size_t)n0 * HID);
#pragma unroll
    for (int i = 0; i < 8; ++i) {
        int Gr = i * 256 + t;
        int row = Gr >> 4, gg = Gr & 15;
        int d = (row << 4) | (gg ^ (row & 7));   // XOR granule swizzle
        ((uint4*)Asub)[d] = Ag[Gr];
        ((uint4*)Bsub)[d] = Bg[Gr];
    }
    __syncthreads();

    const int w = t >> 6, l = t & 63;
    const int wm = (w >> 1) * 64, wn = (w & 1) * 64;
    const int lr = l & 15, lk = l >> 4;
    f32x4 zero = {0.f, 0.f, 0.f, 0.f};
    f32x4 acc[4][4];
#pragma unroll
    for (int mi = 0; mi < 4; ++mi)
#pragma unroll
        for (int ni = 0; ni < 4; ++ni) acc[mi][ni] = zero;

#pragma unroll
    for (int kc = 0; kc < 4; ++kc) {
        f16x8 af[4], bf[4];
#pragma unroll
        for (int mi = 0; mi < 4; ++mi) {
            int row = wm + mi * 16 + lr;
            int gg = kc * 4 + lk;
            af[mi] = *(const f16x8*)&Asub[(row << 7) + ((gg ^ (row & 7)) << 3)];
        }
#pragma unroll
        for (int ni = 0; ni < 4; ++ni) {
            int row = wn + ni * 16 + lr;
            int gg = kc * 4 + lk;
            bf[ni] = *(const f16x8*)&Bsub[(row << 7) + ((gg ^ (row & 7)) << 3)];
        }
#pragma unroll
        for (int mi = 0; mi < 4; ++mi)
#pragma unroll
            for (int ni = 0; ni < 4; ++ni)
                acc[mi][ni] = __builtin_amdgcn_mfma_f32_16x16x32_f16(
                    af[mi], bf[ni], acc[mi][ni], 0, 0, 0);
    }

    // epilogue: transpose through LDS -> contiguous row stores
    __syncthreads();                       // all frag reads done; reuse LDS
    float* ldsf = (float*)lraw;            // [128][132]
#pragma unroll
    for (int mi = 0; mi < 4; ++mi) {
        int lrow = wm + mi * 16 + lk * 4;
#pragma unroll
        for (int ni = 0; ni < 4; ++ni) {
            int lcol = wn + ni * 16 + lr;
#pragma unroll
            for (int r = 0; r < 4; ++r)
                ldsf[(lrow + r) * 132 + lcol] = acc[mi][ni][r];
        }
    }
    __syncthreads();
    const int col = (t * 4) & 127;         // fixed per thread
    const int rbase = t >> 5;
    float4 bv = *(const float4*)&bout[n0 + col];
#pragma unroll
    for (int c = 0; c < 16; ++c) {
        int row = c * 8 + rbase;
        float4 v = *(const float4*)&ldsf[row * 132 + col];
        float4 o;
        o.x = v.x + bv.x; o.y = v.y + bv.y; o.z = v.z + bv.z; o.w = v.w + bv.w;
        o.x = o.x > 0.f ? o.x : 0.f;
        o.y = o.y > 0.f ? o.y : 0.f;
        o.z = o.z > 0.f ? o.z : 0.f;
        o.w = o.w > 0.f ? o.w : 0.f;
        *(float4*)&out[(size_t)(m0 + row) * VOCAB + n0 + col] = o;
    }
}

extern "C" void kernel_launch(void* const* d_in, const int* in_sizes, int n_in,
                              void* d_out, int out_size, void* d_ws, size_t ws_size,
                              hipStream_t stream) {
    const int*   tokens = (const int*)d_in[0];
    const float* emb  = (const float*)d_in[1];
    const float* W0   = (const float*)d_in[2];
    const float* U0   = (const float*)d_in[3];
    const float* b0   = (const float*)d_in[4];
    const float* W1   = (const float*)d_in[5];
    const float* U1   = (const float*)d_in[6];
    const float* b1   = (const float*)d_in[7];
    const float* Wout = (const float*)d_in[8];
    const float* bout = (const float*)d_in[9];
    float* out = (float*)d_out;

    // ws layout: z0base f32 [4096][512] @0 (8,388,608 B)
    //            wp @8,388,608 (393,216 B)
    //            H1 f16 [4096][128] @8,781,824 (1,048,576 B)
    //            WoutT f16 [32000][128] @9,830,400 (8,192,000 B) if ws allows,
    //            else aliases z0base (then transpose must run after the scan).
    char* ws = (char*)d_ws;
    float*    z0base = (float*)ws;
    uint32_t* wp     = (uint32_t*)(ws + 8388608);
    f16*      H1     = (f16*)(ws + 8781824);
    const bool big_ws = ws_size >= (size_t)18100000;
    f16*      WoutT  = big_ws ? (f16*)(ws + 9830400) : (f16*)ws;

    fused_prep<<<640, 256, 0, stream>>>(tokens, emb, W0, b0, U0, W1, U1, z0base, wp);
    scan_fused<<<564, 512, 0, stream>>>(z0base, wp, b1, H1, Wout, WoutT,
                                        big_ws ? 1 : 0);
    if (!big_ws)
        prep_woutT<<<500, 256, 0, stream>>>(Wout, WoutT);
    out_gemm<<<dim3(32, 250), 256, 0, stream>>>(H1, WoutT, bout, out);
}